// Round 7
// baseline (259.969 us; speedup 1.0000x reference)
//
#include <hip/hip_runtime.h>
#include <hip/hip_fp16.h>
#include <math.h>

// ---------------------------------------------------------------------------
// GATv2 x2 + mean-pool + linear, MI355X.
// R27: 2-row software pipelining in the agg body. R25/R26 counters show both
//      agg kernels latency-bound (VALU 37-58%, HBM 7-11%, MFMA 0): the
//      per-row chain (gather -> score -> 4-deep shfl reduce -> exp) x deg/8
//      runs with zero inter-row ILP. Now each wave processes TWO independent
//      rows simultaneously (duplicated state, interleaved chains): 4
//      independent score chains + 4 gathers in flight per iter. Per-row
//      arithmetic/summation order bit-identical to v1 (absmax unchanged).
//      Applied to agg_gemm (4 pairs) and agg_pool (stride-32 pairs).
//      Pipeline unchanged: memset | fill+gemm1 | agg1+gemm2 | agg2+pool+lin.
//      Base = R26 (254.5us; agg_gemm 64us, agg_pool 64us, fill 53us).
// ---------------------------------------------------------------------------

#define ELLC    48
#define OVF_CAP 65536
#define ECHUNK  2048          // edges per fill virtual block

typedef int      vint4 __attribute__((ext_vector_type(4)));
typedef _Float16 half4 __attribute__((ext_vector_type(4)));
typedef float    f32x4 __attribute__((ext_vector_type(4)));

#define GROWS 32

// ---------------- GEMM pieces: stage (global f32 -> LDS) and compute ------
__device__ __forceinline__ void stage_rows_f32(
    int row0, int t, const float* __restrict__ X, int n, float* xS) {
    for (int i = t; i < GROWS * 16; i += 256) {
        int r = row0 + (i >> 4);
        f32x4 v;
        v[0] = 0.f; v[1] = 0.f; v[2] = 0.f; v[3] = 0.f;
        if (r < n)
            v = __builtin_nontemporal_load(
                &((const f32x4*)(X + (size_t)r * 64))[i & 15]);
        ((f32x4*)xS)[i] = v;
    }
}

// xl = in * Wl + bl (fp16 out), xr = in * Wr + br (f32 out), from xS.
__device__ __forceinline__ void gemm_compute(
    int row0, int t,
    const float* __restrict__ Wl, const float* __restrict__ bl,
    const float* __restrict__ Wr, const float* __restrict__ br,
    _Float16* __restrict__ xl, float* __restrict__ xr, int n,
    const float* xS) {
    int h  = t & 63;
    int rb = t >> 6;  // 0..3
    float accl[8], accr[8];
#pragma unroll
    for (int i = 0; i < 8; ++i) { accl[i] = 0.f; accr[i] = 0.f; }
#pragma unroll 4
    for (int d = 0; d < 64; ++d) {
        float wl = Wl[d * 64 + h];   // coalesced 256B, L2-hot
        float wr = Wr[d * 64 + h];
#pragma unroll
        for (int i = 0; i < 8; ++i) {
            float xv = xS[(rb + 4 * i) * 64 + d];  // wave-uniform broadcast
            accl[i] += xv * wl;
            accr[i] += xv * wr;
        }
    }
    float blv = bl[h], brv = br[h];
#pragma unroll
    for (int i = 0; i < 8; ++i) {
        int r = row0 + rb + 4 * i;
        if (r < n) {
            __builtin_nontemporal_store((_Float16)(accl[i] + blv),
                                        &xl[(size_t)r * 64 + h]);
            __builtin_nontemporal_store(accr[i] + brv,
                                        &xr[(size_t)r * 64 + h]);
        }
    }
}

// ---------------- interleaved: XCD-partitioned ELL fill + layer-1 GEMM ----
// 24-block groups: r = b%24. r<16 -> fill vb = (b/24)*16+r (vb&7 == b&7!);
// r>=16 -> gemm vg = (b/24)*8 + (r-16).
__global__ __launch_bounds__(256) void fill_gemm_kernel(
    const int* __restrict__ src, const int* __restrict__ dst,
    int* __restrict__ cnt, unsigned short* __restrict__ ell,
    int* __restrict__ novf, int* __restrict__ ovf_dst, int* __restrict__ ovf_src,
    int E, int N, int psize, int fb, int ggrid,
    const float* __restrict__ X,
    const float* __restrict__ Wl, const float* __restrict__ bl,
    const float* __restrict__ Wr, const float* __restrict__ br,
    _Float16* __restrict__ xl, float* __restrict__ xr) {
    __shared__ float xS[GROWS * 64];
    int b = blockIdx.x;
    int q = b / 24, r = b % 24;
    if (r >= 16) {
        int vg = q * 8 + (r - 16);
        if (vg < ggrid) {
            stage_rows_f32(vg * GROWS, threadIdx.x, X, N, xS);
            __syncthreads();
            gemm_compute(vg * GROWS, threadIdx.x, Wl, bl, Wr, br, xl, xr, N, xS);
        }
        return;
    }
    int vb = q * 16 + r;
    if (vb >= fb) return;
    int t     = threadIdx.x;
    int chunk = vb >> 3;
    int p     = vb & 7;                   // partition == XCD (== b&7)
    int d0    = p * psize;
    int d1    = min(N, d0 + psize);
    int e0    = chunk * ECHUNK;
    int e1    = min(E, e0 + ECHUNK);
    int nq    = (e1 - e0) >> 2;
    const vint4* dst4 = (const vint4*)(dst + e0);
    const vint4* src4 = (const vint4*)(src + e0);

    auto scatter4 = [&](vint4 dv, vint4 sv) {
#pragma unroll
        for (int k = 0; k < 4; ++k) {
            int d = dv[k];
            int s = sv[k];
            if (d >= d0 && d < d1) {
                int pos = atomicAdd(&cnt[d], 1);
                if (pos < ELLC) {
                    ell[d * ELLC + pos] = (unsigned short)s;
                } else {  // P(deg>48) ~ 5e-11 per node
                    int j = atomicAdd(novf, 1);
                    if (j < OVF_CAP) { ovf_dst[j] = d; ovf_src[j] = s; }
                }
            }
        }
    };

    if (nq == (ECHUNK >> 2)) {   // full chunk: both loads up front, 8 chains
        vint4 dvA = __builtin_nontemporal_load(&dst4[t]);
        vint4 svA = __builtin_nontemporal_load(&src4[t]);
        vint4 dvB = __builtin_nontemporal_load(&dst4[t + 256]);
        vint4 svB = __builtin_nontemporal_load(&src4[t + 256]);
        scatter4(dvA, svA);
        scatter4(dvB, svB);
    } else {
        for (int qq = t; qq < nq; qq += 256) {
            vint4 dv = __builtin_nontemporal_load(&dst4[qq]);
            vint4 sv = __builtin_nontemporal_load(&src4[qq]);
            scatter4(dv, sv);
        }
        for (int e = e0 + (nq << 2) + t; e < e1; e += 256) {  // E % 4 tail
            int d = dst[e];
            if (d >= d0 && d < d1) {
                int pos = atomicAdd(&cnt[d], 1);
                int s   = src[e];
                if (pos < ELLC) {
                    ell[d * ELLC + pos] = (unsigned short)s;
                } else {
                    int j = atomicAdd(novf, 1);
                    if (j < OVF_CAP) { ovf_dst[j] = d; ovf_src[j] = s; }
                }
            }
        }
    }
}

// ---------------- agg body: one wave computes TWO h-rows (d0, d1) --------
// wave = 4 groups x 16 lanes. Two independent rows interleaved for ILP:
// 4 gathers + 4 score chains in flight per k-iter. Per-row arithmetic and
// summation order identical to the single-row version.
__device__ __forceinline__ void agg_row2(
    int d0, int d1, bool v1ok,
    int lane, int g, int l,
    const _Float16* __restrict__ xl, const float* __restrict__ xr,
    const int* __restrict__ cnt, const unsigned short* __restrict__ ell,
    const int* __restrict__ novf, const int* __restrict__ ovf_dst,
    const int* __restrict__ ovf_src, float4 att4,
    float& s0o, float4& acc0o, float& s1o, float4& acc1o) {
    int deg0 = cnt[d0];
    int deg1 = v1ok ? cnt[d1] : 0;
    int nd0 = min(deg0, ELLC), nd1 = min(deg1, ELLC);
    float s0 = 0.f, s1 = 0.f;
    float4 acc0 = make_float4(0.f, 0.f, 0.f, 0.f);
    float4 acc1 = make_float4(0.f, 0.f, 0.f, 0.f);

    if (deg0 > 0 || deg1 > 0) {
        int my0 = 0, my1 = 0;
        if (deg0 > 0 && lane < ELLC)
            my0 = (int)__builtin_nontemporal_load(&ell[d0 * ELLC + lane]);
        if (deg1 > 0 && lane < ELLC)
            my1 = (int)__builtin_nontemporal_load(&ell[d1 * ELLC + lane]);
        int if0 = __shfl(my0, 0), if1 = __shfl(my1, 0);

        float4 xr40 = make_float4(0.f, 0.f, 0.f, 0.f), xr41 = xr40;
        if (deg0 > 0) {
            f32x4 tt = __builtin_nontemporal_load(
                &((const f32x4*)(xr + (size_t)d0 * 64))[l]);
            xr40 = make_float4(tt[0], tt[1], tt[2], tt[3]);
        }
        if (deg1 > 0) {
            f32x4 tt = __builtin_nontemporal_load(
                &((const f32x4*)(xr + (size_t)d1 * 64))[l]);
            xr41 = make_float4(tt[0], tt[1], tt[2], tt[3]);
        }

        int ndm = max(nd0, nd1);
#pragma unroll 6
        for (int k = 0; k * 8 < ndm; ++k) {    // k < 6; wave-uniform bound
            int  sa = k * 8 + g, sb = sa + 4;
            bool a0a = sa < nd0, a0b = sb < nd0;
            bool a1a = sa < nd1, a1b = sb < nd1;
            int i00 = __shfl(my0, sa); if (!a0a) i00 = if0;
            int i01 = __shfl(my0, sb); if (!a0b) i01 = if0;
            int i10 = __shfl(my1, sa); if (!a1a) i10 = if1;
            int i11 = __shfl(my1, sb); if (!a1b) i11 = if1;
            // 4 independent 8B gathers in flight
            half4 h00 = ((const half4*)(xl + (size_t)i00 * 64))[l];
            half4 h01 = ((const half4*)(xl + (size_t)i01 * 64))[l];
            half4 h10 = ((const half4*)(xl + (size_t)i10 * 64))[l];
            half4 h11 = ((const half4*)(xl + (size_t)i11 * 64))[l];
            float4 x00 = make_float4((float)h00[0], (float)h00[1], (float)h00[2], (float)h00[3]);
            float4 x01 = make_float4((float)h01[0], (float)h01[1], (float)h01[2], (float)h01[3]);
            float4 x10 = make_float4((float)h10[0], (float)h10[1], (float)h10[2], (float)h10[3]);
            float4 x11 = make_float4((float)h11[0], (float)h11[1], (float)h11[2], (float)h11[3]);
            float z, c00 = 0.f, c01 = 0.f, c10 = 0.f, c11 = 0.f;
            z = x00.x + xr40.x; c00 += ((z > 0.f) ? z : 0.2f * z) * att4.x;
            z = x00.y + xr40.y; c00 += ((z > 0.f) ? z : 0.2f * z) * att4.y;
            z = x00.z + xr40.z; c00 += ((z > 0.f) ? z : 0.2f * z) * att4.z;
            z = x00.w + xr40.w; c00 += ((z > 0.f) ? z : 0.2f * z) * att4.w;
            z = x01.x + xr40.x; c01 += ((z > 0.f) ? z : 0.2f * z) * att4.x;
            z = x01.y + xr40.y; c01 += ((z > 0.f) ? z : 0.2f * z) * att4.y;
            z = x01.z + xr40.z; c01 += ((z > 0.f) ? z : 0.2f * z) * att4.z;
            z = x01.w + xr40.w; c01 += ((z > 0.f) ? z : 0.2f * z) * att4.w;
            z = x10.x + xr41.x; c10 += ((z > 0.f) ? z : 0.2f * z) * att4.x;
            z = x10.y + xr41.y; c10 += ((z > 0.f) ? z : 0.2f * z) * att4.y;
            z = x10.z + xr41.z; c10 += ((z > 0.f) ? z : 0.2f * z) * att4.z;
            z = x10.w + xr41.w; c10 += ((z > 0.f) ? z : 0.2f * z) * att4.w;
            z = x11.x + xr41.x; c11 += ((z > 0.f) ? z : 0.2f * z) * att4.x;
            z = x11.y + xr41.y; c11 += ((z > 0.f) ? z : 0.2f * z) * att4.y;
            z = x11.z + xr41.z; c11 += ((z > 0.f) ? z : 0.2f * z) * att4.z;
            z = x11.w + xr41.w; c11 += ((z > 0.f) ? z : 0.2f * z) * att4.w;
#pragma unroll
            for (int sh = 8; sh >= 1; sh >>= 1) {  // 4 independent reduce chains
                c00 += __shfl_xor(c00, sh);
                c01 += __shfl_xor(c01, sh);
                c10 += __shfl_xor(c10, sh);
                c11 += __shfl_xor(c11, sh);
            }
            float w00 = a0a ? __expf(fminf(c00, 30.f)) : 0.f;
            float w01 = a0b ? __expf(fminf(c01, 30.f)) : 0.f;
            float w10 = a1a ? __expf(fminf(c10, 30.f)) : 0.f;
            float w11 = a1b ? __expf(fminf(c11, 30.f)) : 0.f;
            s0 += w00 + w01;
            acc0.x += w00 * x00.x + w01 * x01.x;
            acc0.y += w00 * x00.y + w01 * x01.y;
            acc0.z += w00 * x00.z + w01 * x01.z;
            acc0.w += w00 * x00.w + w01 * x01.w;
            s1 += w10 + w11;
            acc1.x += w10 * x10.x + w11 * x11.x;
            acc1.y += w10 * x10.y + w11 * x11.y;
            acc1.z += w10 * x10.z + w11 * x11.z;
            acc1.w += w10 * x10.w + w11 * x11.w;
        }
        // overflow fold (deg > ELLC): empty in practice
        auto ovf_fold = [&](int d, int ifirst, float4 xr4, float& s, float4& acc) {
            int no = min(*novf, OVF_CAP);
            for (int j = g; j < no; j += 4) {
                bool active = (ovf_dst[j] == d);
                int  i0     = active ? ovf_src[j] : ifirst;
                half4 h0 = ((const half4*)(xl + (size_t)i0 * 64))[l];
                float4 x0 = make_float4((float)h0[0], (float)h0[1], (float)h0[2], (float)h0[3]);
                float z, c0 = 0.f;
                z = x0.x + xr4.x; c0 += ((z > 0.f) ? z : 0.2f * z) * att4.x;
                z = x0.y + xr4.y; c0 += ((z > 0.f) ? z : 0.2f * z) * att4.y;
                z = x0.z + xr4.z; c0 += ((z > 0.f) ? z : 0.2f * z) * att4.z;
                z = x0.w + xr4.w; c0 += ((z > 0.f) ? z : 0.2f * z) * att4.w;
#pragma unroll
                for (int sh = 8; sh >= 1; sh >>= 1) c0 += __shfl_xor(c0, sh);
                float w0 = active ? __expf(fminf(c0, 30.f)) : 0.f;
                s += w0;
                acc.x += w0 * x0.x;
                acc.y += w0 * x0.y;
                acc.z += w0 * x0.z;
                acc.w += w0 * x0.w;
            }
        };
        if (deg0 > ELLC) ovf_fold(d0, if0, xr40, s0, acc0);
        if (deg1 > ELLC) ovf_fold(d1, if1, xr41, s1, acc1);

        // merge the 4 group partial sums, xor 16 then xor 32 (10 indep chains)
#pragma unroll
        for (int mask = 16; mask <= 32; mask <<= 1) {
            s0     += __shfl_xor(s0, mask);
            acc0.x += __shfl_xor(acc0.x, mask);
            acc0.y += __shfl_xor(acc0.y, mask);
            acc0.z += __shfl_xor(acc0.z, mask);
            acc0.w += __shfl_xor(acc0.w, mask);
            s1     += __shfl_xor(s1, mask);
            acc1.x += __shfl_xor(acc1.x, mask);
            acc1.y += __shfl_xor(acc1.y, mask);
            acc1.z += __shfl_xor(acc1.z, mask);
            acc1.w += __shfl_xor(acc1.w, mask);
        }
    }
    s0o = s0; acc0o = acc0; s1o = s1; acc1o = acc1;
}

// ---------------- fused: agg1 (32 dst rows -> LDS) + layer-2 dual GEMM ----
// block = 32 consecutive dst rows; 4 waves x 4 row-PAIRS each.
__global__ __launch_bounds__(256) void agg_gemm_kernel(
    const _Float16* __restrict__ xl1, const float* __restrict__ xr1,
    const int* __restrict__ cnt, const unsigned short* __restrict__ ell,
    const int* __restrict__ novf, const int* __restrict__ ovf_dst,
    const int* __restrict__ ovf_src,
    const float* __restrict__ att, const float* __restrict__ bias,
    const float* __restrict__ Wl2, const float* __restrict__ bl2,
    const float* __restrict__ Wr2, const float* __restrict__ br2,
    _Float16* __restrict__ xl2, float* __restrict__ xr2, int n) {
    __shared__ float xS[GROWS * 64];
    int t    = threadIdx.x;
    int w    = t >> 6;
    int lane = t & 63;
    int g    = lane >> 4;
    int l    = lane & 15;
    int row0 = blockIdx.x * GROWS;

    float4 att4 = ((const float4*)att)[l];
    float4 b4   = ((const float4*)bias)[l];

    // ---- phase 1: each wave aggregates 4 row-pairs into LDS (f32, relu'd) -
    for (int i = 0; i < 8; i += 2) {
        int rr = w * 8 + i;
        int d0 = row0 + rr;
        int d1 = d0 + 1;
        float s0, s1; float4 a0, a1;
        if (d0 < n) {
            agg_row2(d0, d1, d1 < n, lane, g, l, xl1, xr1, cnt, ell,
                     novf, ovf_dst, ovf_src, att4, s0, a0, s1, a1);
        } else {
            s0 = s1 = 0.f;
            a0 = make_float4(0.f, 0.f, 0.f, 0.f); a1 = a0;
        }
        if (g == 0) {
            float4 hv0 = make_float4(0.f, 0.f, 0.f, 0.f), hv1 = hv0;
            if (d0 < n) {
                float inv = (s0 > 0.f) ? (1.f / s0) : 0.f;
                hv0.x = fmaxf(a0.x * inv + b4.x, 0.f);
                hv0.y = fmaxf(a0.y * inv + b4.y, 0.f);
                hv0.z = fmaxf(a0.z * inv + b4.z, 0.f);
                hv0.w = fmaxf(a0.w * inv + b4.w, 0.f);
            }
            if (d1 < n) {
                float inv = (s1 > 0.f) ? (1.f / s1) : 0.f;
                hv1.x = fmaxf(a1.x * inv + b4.x, 0.f);
                hv1.y = fmaxf(a1.y * inv + b4.y, 0.f);
                hv1.z = fmaxf(a1.z * inv + b4.z, 0.f);
                hv1.w = fmaxf(a1.w * inv + b4.w, 0.f);
            }
            ((float4*)(xS + rr * 64))[l]       = hv0;
            ((float4*)(xS + (rr + 1) * 64))[l] = hv1;
        }
    }
    __syncthreads();
    // ---- phase 2: layer-2 dual GEMM straight from LDS ----
    gemm_compute(row0, t, Wl2, bl2, Wr2, br2, xl2, xr2, n, xS);
}

// ---------------- fused: agg2 + per-graph mean pool + final linear --------
// block g = graph g (batch sorted -> contiguous range). 1024 thr = 16 waves;
// wave w processes row pairs (start+w+32m, +16) for ILP.
__global__ __launch_bounds__(1024) void agg_pool_final_kernel(
    const _Float16* __restrict__ xl, const float* __restrict__ xr,
    const int* __restrict__ cnt, const unsigned short* __restrict__ ell,
    const int* __restrict__ novf, const int* __restrict__ ovf_dst,
    const int* __restrict__ ovf_src,
    const float* __restrict__ att, const float* __restrict__ bias,
    const int* __restrict__ batch,
    const float* __restrict__ lin_w, const float* __restrict__ lin_b,
    float* __restrict__ out, int N, int G) {
    int gid  = blockIdx.x;   // graph id
    int t    = threadIdx.x;
    int w    = t >> 6;       // 0..15
    int lane = t & 63;
    int g    = lane >> 4;
    int l    = lane & 15;

    auto lb = [&](int key) {
        int lo = 0, hi = N;
        while (lo < hi) {
            int mid = (lo + hi) >> 1;
            if (batch[mid] < key) lo = mid + 1; else hi = mid;
        }
        return lo;
    };
    int start = lb(gid), end = lb(gid + 1);

    float4 att4 = ((const float4*)att)[l];
    float4 b4   = ((const float4*)bias)[l];

    float4 pool4 = make_float4(0.f, 0.f, 0.f, 0.f);
    for (int d0 = start + w; d0 < end; d0 += 32) {
        int d1 = d0 + 16;
        float s0, s1; float4 a0, a1;
        agg_row2(d0, d1, d1 < end, lane, g, l, xl, xr, cnt, ell,
                 novf, ovf_dst, ovf_src, att4, s0, a0, s1, a1);
        float inv0 = (s0 > 0.f) ? (1.f / s0) : 0.f;
        pool4.x += fmaxf(a0.x * inv0 + b4.x, 0.f);
        pool4.y += fmaxf(a0.y * inv0 + b4.y, 0.f);
        pool4.z += fmaxf(a0.z * inv0 + b4.z, 0.f);
        pool4.w += fmaxf(a0.w * inv0 + b4.w, 0.f);
        if (d1 < end) {
            float inv1 = (s1 > 0.f) ? (1.f / s1) : 0.f;
            pool4.x += fmaxf(a1.x * inv1 + b4.x, 0.f);
            pool4.y += fmaxf(a1.y * inv1 + b4.y, 0.f);
            pool4.z += fmaxf(a1.z * inv1 + b4.z, 0.f);
            pool4.w += fmaxf(a1.w * inv1 + b4.w, 0.f);
        }
    }

    __shared__ float part[16][64];
    __shared__ float pooled[64];
    if (g == 0) ((float4*)part[w])[l] = pool4;   // groups hold identical vals
    __syncthreads();
    if (t < 64) {
        float sum = 0.f;
#pragma unroll
        for (int ww = 0; ww < 16; ++ww) sum += part[ww][t];
        pooled[t] = sum / fmaxf((float)(end - start), 1.f);
    }
    __syncthreads();
    if (t < 32) {
        float a = 0.f;
#pragma unroll 8
        for (int hh = 0; hh < 64; ++hh) a += pooled[hh] * lin_w[hh * 32 + t];
        out[gid * 32 + t] = a + lin_b[t];
    }
}

extern "C" void kernel_launch(void* const* d_in, const int* in_sizes, int n_in,
                              void* d_out, int out_size, void* d_ws, size_t ws_size,
                              hipStream_t stream) {
    const float* x     = (const float*)d_in[0];
    const int*   ei    = (const int*)d_in[1];
    const int*   batch = (const int*)d_in[2];
    const float* Wl1   = (const float*)d_in[3];
    const float* bl1   = (const float*)d_in[4];
    const float* Wr1   = (const float*)d_in[5];
    const float* br1   = (const float*)d_in[6];
    const float* att1  = (const float*)d_in[7];
    const float* bias1 = (const float*)d_in[8];
    const float* Wl2   = (const float*)d_in[9];
    const float* bl2   = (const float*)d_in[10];
    const float* Wr2   = (const float*)d_in[11];
    const float* br2   = (const float*)d_in[12];
    const float* att2  = (const float*)d_in[13];
    const float* bias2 = (const float*)d_in[14];
    const float* lin_w = (const float*)d_in[15];
    const float* lin_b = (const float*)d_in[16];
    float* out = (float*)d_out;

    const int N = in_sizes[0] / 64;
    const int E = in_sizes[1] / 2;
    const int G = out_size / 32;
    const int* src = ei;
    const int* dst = ei + E;

    // ---- workspace carve-up (256B-aligned) ----
    char*  ws  = (char*)d_ws;
    size_t off = 0;
    auto alloc = [&](size_t bytes) -> void* {
        void* p = ws + off;
        off += bytes;
        off = (off + 255) & ~(size_t)255;
        return p;
    };
    _Float16* xl1  = (_Float16*)alloc((size_t)N * 64 * sizeof(_Float16));
    float* xr1     = (float*)alloc((size_t)N * 64 * sizeof(float));
    _Float16* xl2  = (_Float16*)alloc((size_t)N * 64 * sizeof(_Float16));
    float* xr2     = (float*)alloc((size_t)N * 64 * sizeof(float));
    // zeroed region (contiguous): cnt, novf
    int*   cnt     = (int*)alloc((size_t)N * sizeof(int));
    int*   novf    = (int*)alloc(256);
    char*  zend    = ws + off;
    unsigned short* ell = (unsigned short*)alloc((size_t)N * ELLC * sizeof(unsigned short));
    int*   ovf_dst = (int*)alloc((size_t)OVF_CAP * sizeof(int));
    int*   ovf_src = (int*)alloc((size_t)OVF_CAP * sizeof(int));

    (void)hipMemsetAsync(cnt, 0, (size_t)(zend - (char*)cnt), stream);

    int ggrid  = (N + GROWS - 1) / GROWS;        // 32-row tiles
    int nchunk = (E + ECHUNK - 1) / ECHUNK;
    int fb     = nchunk * 8;                     // fill virtual blocks (x8 XCD)
    int psize  = (N + 7) / 8;                    // dst partition size
    // interleaved grid: groups of 24 = 16 fill + 8 gemm
    int ngroups = max((fb + 15) / 16, (ggrid + 7) / 8);
    int igrid   = ngroups * 24;

    // ---- interleaved: XCD-partitioned ELL fill + layer-1 dual GEMM ----
    fill_gemm_kernel<<<igrid, 256, 0, stream>>>(
        src, dst, cnt, ell, novf, ovf_dst, ovf_src, E, N, psize, fb, ggrid,
        x, Wl1, bl1, Wr1, br1, xl1, xr1);

    // ---- fused agg1 (-> LDS) + layer-2 dual GEMM (-> xl2/xr2) ----
    agg_gemm_kernel<<<ggrid, 256, 0, stream>>>(
        xl1, xr1, cnt, ell, novf, ovf_dst, ovf_src, att1, bias1,
        Wl2, bl2, Wr2, br2, xl2, xr2, N);

    // ---- fused agg2 + per-graph mean pool + final linear ----
    agg_pool_final_kernel<<<G, 1024, 0, stream>>>(
        xl2, xr2, cnt, ell, novf, ovf_dst, ovf_src, att2, bias2,
        batch, lin_w, lin_b, out, N, G);
}

// Round 8
// 258.747 us; speedup vs baseline: 1.0047x; 1.0047x over previous
//
#include <hip/hip_runtime.h>
#include <hip/hip_fp16.h>
#include <math.h>

// ---------------------------------------------------------------------------
// GATv2 x2 + mean-pool + linear, MI355X.
// R28: 8x8 agg layout. Evidence: R22 (prefetch-all null) + R27 (2-row ILP
//      regression) => agg is NOT exposed-latency-bound; it's a mix of
//      scattered-read throughput and per-row instruction cost. Attack the
//      instruction half: wave = 8 groups x 8 lanes x 8 features (16B/lane
//      loads), 16 slots/k-iter (deg<=16 rows: ONE iter), 3-step score
//      reduce, 8 rows per gather instruction (2x MLP/instr). Same bytes per
//      edge; fp32 reorder only (absmax ~1e-3). R27 pairing reverted.
//      Null branch: aggs unchanged => scattered-128B ceiling is binding =>
//      structural roofline (fill 53 atomic wall + 2x agg scatter wall).
//      Base = R26/R27 (254-260us; agg_gemm 64-67, agg_pool 63-64, fill 53).
// ---------------------------------------------------------------------------

#define ELLC    48
#define OVF_CAP 65536
#define ECHUNK  2048          // edges per fill virtual block

typedef int      vint4 __attribute__((ext_vector_type(4)));
typedef _Float16 half8 __attribute__((ext_vector_type(8)));   // 16B
typedef float    f32x4 __attribute__((ext_vector_type(4)));
typedef float    f32x8 __attribute__((ext_vector_type(8)));   // 32B

#define GROWS 32

// ---------------- GEMM pieces: stage (global f32 -> LDS) and compute ------
__device__ __forceinline__ void stage_rows_f32(
    int row0, int t, const float* __restrict__ X, int n, float* xS) {
    for (int i = t; i < GROWS * 16; i += 256) {
        int r = row0 + (i >> 4);
        f32x4 v;
        v[0] = 0.f; v[1] = 0.f; v[2] = 0.f; v[3] = 0.f;
        if (r < n)
            v = __builtin_nontemporal_load(
                &((const f32x4*)(X + (size_t)r * 64))[i & 15]);
        ((f32x4*)xS)[i] = v;
    }
}

// xl = in * Wl + bl (fp16 out), xr = in * Wr + br (f32 out), from xS.
__device__ __forceinline__ void gemm_compute(
    int row0, int t,
    const float* __restrict__ Wl, const float* __restrict__ bl,
    const float* __restrict__ Wr, const float* __restrict__ br,
    _Float16* __restrict__ xl, float* __restrict__ xr, int n,
    const float* xS) {
    int h  = t & 63;
    int rb = t >> 6;  // 0..3
    float accl[8], accr[8];
#pragma unroll
    for (int i = 0; i < 8; ++i) { accl[i] = 0.f; accr[i] = 0.f; }
#pragma unroll 4
    for (int d = 0; d < 64; ++d) {
        float wl = Wl[d * 64 + h];   // coalesced 256B, L2-hot
        float wr = Wr[d * 64 + h];
#pragma unroll
        for (int i = 0; i < 8; ++i) {
            float xv = xS[(rb + 4 * i) * 64 + d];  // wave-uniform broadcast
            accl[i] += xv * wl;
            accr[i] += xv * wr;
        }
    }
    float blv = bl[h], brv = br[h];
#pragma unroll
    for (int i = 0; i < 8; ++i) {
        int r = row0 + rb + 4 * i;
        if (r < n) {
            __builtin_nontemporal_store((_Float16)(accl[i] + blv),
                                        &xl[(size_t)r * 64 + h]);
            __builtin_nontemporal_store(accr[i] + brv,
                                        &xr[(size_t)r * 64 + h]);
        }
    }
}

// ---------------- interleaved: XCD-partitioned ELL fill + layer-1 GEMM ----
// 24-block groups: r = b%24. r<16 -> fill vb = (b/24)*16+r (vb&7 == b&7!);
// r>=16 -> gemm vg = (b/24)*8 + (r-16).
__global__ __launch_bounds__(256) void fill_gemm_kernel(
    const int* __restrict__ src, const int* __restrict__ dst,
    int* __restrict__ cnt, unsigned short* __restrict__ ell,
    int* __restrict__ novf, int* __restrict__ ovf_dst, int* __restrict__ ovf_src,
    int E, int N, int psize, int fb, int ggrid,
    const float* __restrict__ X,
    const float* __restrict__ Wl, const float* __restrict__ bl,
    const float* __restrict__ Wr, const float* __restrict__ br,
    _Float16* __restrict__ xl, float* __restrict__ xr) {
    __shared__ float xS[GROWS * 64];
    int b = blockIdx.x;
    int q = b / 24, r = b % 24;
    if (r >= 16) {
        int vg = q * 8 + (r - 16);
        if (vg < ggrid) {
            stage_rows_f32(vg * GROWS, threadIdx.x, X, N, xS);
            __syncthreads();
            gemm_compute(vg * GROWS, threadIdx.x, Wl, bl, Wr, br, xl, xr, N, xS);
        }
        return;
    }
    int vb = q * 16 + r;
    if (vb >= fb) return;
    int t     = threadIdx.x;
    int chunk = vb >> 3;
    int p     = vb & 7;                   // partition == XCD (== b&7)
    int d0    = p * psize;
    int d1    = min(N, d0 + psize);
    int e0    = chunk * ECHUNK;
    int e1    = min(E, e0 + ECHUNK);
    int nq    = (e1 - e0) >> 2;
    const vint4* dst4 = (const vint4*)(dst + e0);
    const vint4* src4 = (const vint4*)(src + e0);

    auto scatter4 = [&](vint4 dv, vint4 sv) {
#pragma unroll
        for (int k = 0; k < 4; ++k) {
            int d = dv[k];
            int s = sv[k];
            if (d >= d0 && d < d1) {
                int pos = atomicAdd(&cnt[d], 1);
                if (pos < ELLC) {
                    ell[d * ELLC + pos] = (unsigned short)s;
                } else {  // P(deg>48) ~ 5e-11 per node
                    int j = atomicAdd(novf, 1);
                    if (j < OVF_CAP) { ovf_dst[j] = d; ovf_src[j] = s; }
                }
            }
        }
    };

    if (nq == (ECHUNK >> 2)) {   // full chunk: both loads up front, 8 chains
        vint4 dvA = __builtin_nontemporal_load(&dst4[t]);
        vint4 svA = __builtin_nontemporal_load(&src4[t]);
        vint4 dvB = __builtin_nontemporal_load(&dst4[t + 256]);
        vint4 svB = __builtin_nontemporal_load(&src4[t + 256]);
        scatter4(dvA, svA);
        scatter4(dvB, svB);
    } else {
        for (int qq = t; qq < nq; qq += 256) {
            vint4 dv = __builtin_nontemporal_load(&dst4[qq]);
            vint4 sv = __builtin_nontemporal_load(&src4[qq]);
            scatter4(dv, sv);
        }
        for (int e = e0 + (nq << 2) + t; e < e1; e += 256) {  // E % 4 tail
            int d = dst[e];
            if (d >= d0 && d < d1) {
                int pos = atomicAdd(&cnt[d], 1);
                int s   = src[e];
                if (pos < ELLC) {
                    ell[d * ELLC + pos] = (unsigned short)s;
                } else {
                    int j = atomicAdd(novf, 1);
                    if (j < OVF_CAP) { ovf_dst[j] = d; ovf_src[j] = s; }
                }
            }
        }
    }
}

// ---------------- agg body (8x8 layout): one wave computes h-row of d -----
// wave = 8 groups x 8 lanes; lane owns 8 features (16B gathers); 16 edge
// slots per k-iter (deg<=16 -> single iter). After final merge, every lane
// holds s and its 8 features of acc.
__device__ __forceinline__ void agg_row8(
    int d, int lane, int g, int l,     // g = lane>>3, l = lane&7
    const _Float16* __restrict__ xl, const float* __restrict__ xr,
    const int* __restrict__ cnt, const unsigned short* __restrict__ ell,
    const int* __restrict__ novf, const int* __restrict__ ovf_dst,
    const int* __restrict__ ovf_src,
    f32x8 att8, float& s_o, f32x8& acc_o) {
    int deg_d = cnt[d];
    int nd  = min(deg_d, ELLC);
    float s = 0.f;
    f32x8 acc;
#pragma unroll
    for (int j = 0; j < 8; ++j) acc[j] = 0.f;

    if (deg_d > 0) {
        // one coalesced 96B read of the whole ELL row; lane i holds slot i
        int myidx = 0;
        if (lane < ELLC)
            myidx = (int)__builtin_nontemporal_load(&ell[d * ELLC + lane]);
        int i_first = __shfl(myidx, 0);

        f32x8 xr8 = __builtin_nontemporal_load(
            &((const f32x8*)(xr + (size_t)d * 64))[l]);

#pragma unroll 3
        for (int k = 0; k * 16 < nd; ++k) {   // <= 3 iters; wave-uniform
            int  sa = k * 16 + g, sb = sa + 8;
            bool aa = sa < nd,    ab = sb < nd;
            int  i0 = __shfl(myidx, sa); if (!aa) i0 = i_first;
            int  i1 = __shfl(myidx, sb); if (!ab) i1 = i_first;
            // 16B gathers: 8 lanes x 16B = full 128B row per group
            half8 h0 = ((const half8*)(xl + (size_t)i0 * 64))[l];
            half8 h1 = ((const half8*)(xl + (size_t)i1 * 64))[l];
            float c0 = 0.f, c1 = 0.f;
#pragma unroll
            for (int j = 0; j < 8; ++j) {
                float z0 = (float)h0[j] + xr8[j];
                float z1 = (float)h1[j] + xr8[j];
                c0 += ((z0 > 0.f) ? z0 : 0.2f * z0) * att8[j];
                c1 += ((z1 > 0.f) ? z1 : 0.2f * z1) * att8[j];
            }
#pragma unroll
            for (int sh = 4; sh >= 1; sh >>= 1) {  // 8-lane reduce, 3 steps
                c0 += __shfl_xor(c0, sh);
                c1 += __shfl_xor(c1, sh);
            }
            float w0 = aa ? __expf(fminf(c0, 30.f)) : 0.f;
            float w1 = ab ? __expf(fminf(c1, 30.f)) : 0.f;
            s += w0 + w1;
#pragma unroll
            for (int j = 0; j < 8; ++j)
                acc[j] += w0 * (float)h0[j] + w1 * (float)h1[j];
        }
        // overflow fold (deg > ELLC): empty in practice
        if (deg_d > ELLC) {
            int no = min(*novf, OVF_CAP);
            for (int j = g; j < no; j += 8) {
                bool active = (ovf_dst[j] == d);
                int  i0     = active ? ovf_src[j] : i_first;
                half8 h0 = ((const half8*)(xl + (size_t)i0 * 64))[l];
                float c0 = 0.f;
#pragma unroll
                for (int jj = 0; jj < 8; ++jj) {
                    float z = (float)h0[jj] + xr8[jj];
                    c0 += ((z > 0.f) ? z : 0.2f * z) * att8[jj];
                }
#pragma unroll
                for (int sh = 4; sh >= 1; sh >>= 1) c0 += __shfl_xor(c0, sh);
                float w0 = active ? __expf(fminf(c0, 30.f)) : 0.f;
                s += w0;
#pragma unroll
                for (int jj = 0; jj < 8; ++jj) acc[jj] += w0 * (float)h0[jj];
            }
        }
        // merge the 8 group partials: xor 8, 16, 32
#pragma unroll
        for (int mask = 8; mask <= 32; mask <<= 1) {
            s += __shfl_xor(s, mask);
#pragma unroll
            for (int j = 0; j < 8; ++j) acc[j] += __shfl_xor(acc[j], mask);
        }
    }
    s_o = s; acc_o = acc;
}

// ---------------- fused: agg1 (32 dst rows -> LDS) + layer-2 dual GEMM ----
// block = 32 consecutive dst rows; 4 waves x 8 sequential dst each.
__global__ __launch_bounds__(256) void agg_gemm_kernel(
    const _Float16* __restrict__ xl1, const float* __restrict__ xr1,
    const int* __restrict__ cnt, const unsigned short* __restrict__ ell,
    const int* __restrict__ novf, const int* __restrict__ ovf_dst,
    const int* __restrict__ ovf_src,
    const float* __restrict__ att, const float* __restrict__ bias,
    const float* __restrict__ Wl2, const float* __restrict__ bl2,
    const float* __restrict__ Wr2, const float* __restrict__ br2,
    _Float16* __restrict__ xl2, float* __restrict__ xr2, int n) {
    __shared__ float xS[GROWS * 64];
    int t    = threadIdx.x;
    int w    = t >> 6;
    int lane = t & 63;
    int g    = lane >> 3;
    int l    = lane & 7;
    int row0 = blockIdx.x * GROWS;

    f32x8 att8 = ((const f32x8*)att)[l];
    f32x8 b8   = ((const f32x8*)bias)[l];

    // ---- phase 1: each wave aggregates 8 dst rows into LDS (f32, relu'd) --
    for (int i = 0; i < 8; ++i) {
        int rr = w * 8 + i;
        int d  = row0 + rr;
        float s; f32x8 acc;
        if (d < n) {
            agg_row8(d, lane, g, l, xl1, xr1, cnt, ell, novf, ovf_dst,
                     ovf_src, att8, s, acc);
        } else {
            s = 0.f;
#pragma unroll
            for (int j = 0; j < 8; ++j) acc[j] = 0.f;
        }
        if (g == 0) {                       // lanes 0..7 write the row
            f32x8 hv;
            float inv = (s > 0.f) ? (1.f / s) : 0.f;  // deg-0 -> relu(bias)
#pragma unroll
            for (int j = 0; j < 8; ++j)
                hv[j] = (d < n) ? fmaxf(acc[j] * inv + b8[j], 0.f) : 0.f;
            ((f32x8*)(xS + rr * 64))[l] = hv;
        }
    }
    __syncthreads();
    // ---- phase 2: layer-2 dual GEMM straight from LDS ----
    gemm_compute(row0, t, Wl2, bl2, Wr2, br2, xl2, xr2, n, xS);
}

// ---------------- fused: agg2 + per-graph mean pool + final linear --------
// block g = graph g (batch sorted -> contiguous range). 1024 thr = 16 waves;
// wave w agg-rows nodes start+w, +16, ... accumulating relu'd h into a
// pooled register partial; LDS-reduce; 64x32 linear.
__global__ __launch_bounds__(1024) void agg_pool_final_kernel(
    const _Float16* __restrict__ xl, const float* __restrict__ xr,
    const int* __restrict__ cnt, const unsigned short* __restrict__ ell,
    const int* __restrict__ novf, const int* __restrict__ ovf_dst,
    const int* __restrict__ ovf_src,
    const float* __restrict__ att, const float* __restrict__ bias,
    const int* __restrict__ batch,
    const float* __restrict__ lin_w, const float* __restrict__ lin_b,
    float* __restrict__ out, int N, int G) {
    int gid  = blockIdx.x;   // graph id
    int t    = threadIdx.x;
    int w    = t >> 6;       // 0..15
    int lane = t & 63;
    int g    = lane >> 3;
    int l    = lane & 7;

    auto lb = [&](int key) {
        int lo = 0, hi = N;
        while (lo < hi) {
            int mid = (lo + hi) >> 1;
            if (batch[mid] < key) lo = mid + 1; else hi = mid;
        }
        return lo;
    };
    int start = lb(gid), end = lb(gid + 1);

    f32x8 att8 = ((const f32x8*)att)[l];
    f32x8 b8   = ((const f32x8*)bias)[l];

    f32x8 pool8;
#pragma unroll
    for (int j = 0; j < 8; ++j) pool8[j] = 0.f;

    for (int d = start + w; d < end; d += 16) {
        float s; f32x8 acc;
        agg_row8(d, lane, g, l, xl, xr, cnt, ell, novf, ovf_dst, ovf_src,
                 att8, s, acc);
        float inv = (s > 0.f) ? (1.f / s) : 0.f;   // deg-0 -> relu(bias)
#pragma unroll
        for (int j = 0; j < 8; ++j)
            pool8[j] += fmaxf(acc[j] * inv + b8[j], 0.f);
    }

    __shared__ float part[16][64];
    __shared__ float pooled[64];
    if (g == 0) ((f32x8*)part[w])[l] = pool8;   // groups hold identical vals
    __syncthreads();
    if (t < 64) {
        float sum = 0.f;
#pragma unroll
        for (int ww = 0; ww < 16; ++ww) sum += part[ww][t];
        pooled[t] = sum / fmaxf((float)(end - start), 1.f);
    }
    __syncthreads();
    if (t < 32) {
        float a = 0.f;
#pragma unroll 8
        for (int hh = 0; hh < 64; ++hh) a += pooled[hh] * lin_w[hh * 32 + t];
        out[gid * 32 + t] = a + lin_b[t];
    }
}

extern "C" void kernel_launch(void* const* d_in, const int* in_sizes, int n_in,
                              void* d_out, int out_size, void* d_ws, size_t ws_size,
                              hipStream_t stream) {
    const float* x     = (const float*)d_in[0];
    const int*   ei    = (const int*)d_in[1];
    const int*   batch = (const int*)d_in[2];
    const float* Wl1   = (const float*)d_in[3];
    const float* bl1   = (const float*)d_in[4];
    const float* Wr1   = (const float*)d_in[5];
    const float* br1   = (const float*)d_in[6];
    const float* att1  = (const float*)d_in[7];
    const float* bias1 = (const float*)d_in[8];
    const float* Wl2   = (const float*)d_in[9];
    const float* bl2   = (const float*)d_in[10];
    const float* Wr2   = (const float*)d_in[11];
    const float* br2   = (const float*)d_in[12];
    const float* att2  = (const float*)d_in[13];
    const float* bias2 = (const float*)d_in[14];
    const float* lin_w = (const float*)d_in[15];
    const float* lin_b = (const float*)d_in[16];
    float* out = (float*)d_out;

    const int N = in_sizes[0] / 64;
    const int E = in_sizes[1] / 2;
    const int G = out_size / 32;
    const int* src = ei;
    const int* dst = ei + E;

    // ---- workspace carve-up (256B-aligned) ----
    char*  ws  = (char*)d_ws;
    size_t off = 0;
    auto alloc = [&](size_t bytes) -> void* {
        void* p = ws + off;
        off += bytes;
        off = (off + 255) & ~(size_t)255;
        return p;
    };
    _Float16* xl1  = (_Float16*)alloc((size_t)N * 64 * sizeof(_Float16));
    float* xr1     = (float*)alloc((size_t)N * 64 * sizeof(float));
    _Float16* xl2  = (_Float16*)alloc((size_t)N * 64 * sizeof(_Float16));
    float* xr2     = (float*)alloc((size_t)N * 64 * sizeof(float));
    // zeroed region (contiguous): cnt, novf
    int*   cnt     = (int*)alloc((size_t)N * sizeof(int));
    int*   novf    = (int*)alloc(256);
    char*  zend    = ws + off;
    unsigned short* ell = (unsigned short*)alloc((size_t)N * ELLC * sizeof(unsigned short));
    int*   ovf_dst = (int*)alloc((size_t)OVF_CAP * sizeof(int));
    int*   ovf_src = (int*)alloc((size_t)OVF_CAP * sizeof(int));

    (void)hipMemsetAsync(cnt, 0, (size_t)(zend - (char*)cnt), stream);

    int ggrid  = (N + GROWS - 1) / GROWS;        // 32-row tiles
    int nchunk = (E + ECHUNK - 1) / ECHUNK;
    int fb     = nchunk * 8;                     // fill virtual blocks (x8 XCD)
    int psize  = (N + 7) / 8;                    // dst partition size
    // interleaved grid: groups of 24 = 16 fill + 8 gemm
    int ngroups = max((fb + 15) / 16, (ggrid + 7) / 8);
    int igrid   = ngroups * 24;

    // ---- interleaved: XCD-partitioned ELL fill + layer-1 dual GEMM ----
    fill_gemm_kernel<<<igrid, 256, 0, stream>>>(
        src, dst, cnt, ell, novf, ovf_dst, ovf_src, E, N, psize, fb, ggrid,
        x, Wl1, bl1, Wr1, br1, xl1, xr1);

    // ---- fused agg1 (-> LDS) + layer-2 dual GEMM (-> xl2/xr2) ----
    agg_gemm_kernel<<<ggrid, 256, 0, stream>>>(
        xl1, xr1, cnt, ell, novf, ovf_dst, ovf_src, att1, bias1,
        Wl2, bl2, Wr2, br2, xl2, xr2, N);

    // ---- fused agg2 + per-graph mean pool + final linear ----
    agg_pool_final_kernel<<<G, 1024, 0, stream>>>(
        xl2, xr2, cnt, ell, novf, ovf_dst, ovf_src, att2, bias2,
        batch, lin_w, lin_b, out, N, G);
}